// Round 3
// baseline (984.319 us; speedup 1.0000x reference)
//
#include <hip/hip_runtime.h>

// ---------------------------------------------------------------------------
// AGCN block: a/b 1x1 convs -> scores -> softmax(+A) -> z = x@att -> y = Wd@z
// N=64 C=64 T=256 V=25 S=3 OC=64 IC=32. All fp32 (no fp32 MFMA on CDNA4 ->
// vector-ALU bound, roofline ~166us @157TF). Strategy: make every inner loop
// "1 divergent read + 16 v_fmac with SGPR (s_load_dwordx16) weight operand".
// ---------------------------------------------------------------------------

#define NCHUNK    16                     // t-chunks per n in K1 (occupancy)
#define ATT_OFF   0                      // [N][S][25][32] padded att
#define ATT_SZ    (64*3*25*32)           // 153600
#define PART_OFF  153600                 // [N][NCHUNK][S][625] score partials
#define PART_SZ   (64*NCHUNK*3*625)      // 1920000
#define WAT_OFF   (PART_OFF + PART_SZ)   // [S][C][IC]
#define WBT_OFF   (WAT_OFF + 3*64*32)    // [S][C][IC]
#define WDT_OFF   (WBT_OFF + 3*64*32)    // [S][C][OC]
#define ALPHA_OFF (WDT_OFF + 3*64*64)    // [OC]
#define BETA_OFF  (ALPHA_OFF + 64)       // [OC]
// total ws: ~2.1M floats = 8.4 MB

// --------------------------- K0: weight prep -------------------------------
__global__ __launch_bounds__(256) void k0_prep(
    float* __restrict__ wsf,
    const float* __restrict__ Wa, const float* __restrict__ Wb,
    const float* __restrict__ Wd, const float* __restrict__ bd,
    const float* __restrict__ gamma, const float* __restrict__ beta)
{
  int idx = blockIdx.x * 256 + threadIdx.x;
  if (idx < 6144) {                       // WaT/WbT: [s][c][i] <- [s][i][c]
    int s = idx / 2048, r = idx - s * 2048, c = r >> 5, i = r & 31;
    wsf[WAT_OFF + idx] = Wa[s * 2048 + i * 64 + c];
    wsf[WBT_OFF + idx] = Wb[s * 2048 + i * 64 + c];
  }
  if (idx < 12288) {                      // WdT: [s][c][o] <- [s][o][c]
    int s = idx / 4096, r = idx - s * 4096, c = r >> 6, o = r & 63;
    wsf[WDT_OFF + idx] = Wd[s * 4096 + o * 64 + c];
  }
  if (idx < 64) {                         // fused BN(inference) + bias-sum
    float al = gamma[idx] * rsqrtf(1.0f + 1e-5f);
    wsf[ALPHA_OFF + idx] = al;
    float bs = bd[idx] + bd[64 + idx] + bd[128 + idx];
    wsf[BETA_OFF + idx] = beta[idx] + al * bs;
  }
}

// ------------------- K1: conv a,b + score partial accumulation -------------
// grid (n, chunk of 16 t) = 64*16 = 1024 blocks, 256 threads (4 blocks/CU,
// LDS-capped). Per (sub,s): conv 4 t's (lanes=(t,v), regs=16 i's, Wa/Wb via
// s_load), then 5x5-register-tiled scores into LDS red[s] (2.5 FMA/ds_read).
__global__ __launch_bounds__(256) void k1_scores(
    const float* __restrict__ x,
    const float* __restrict__ WaT, const float* __restrict__ WbT,
    const float* __restrict__ ba, const float* __restrict__ bb,
    float* __restrict__ part)
{
  const int nb = blockIdx.x;
  const int n = nb >> 4;
  const int ch = nb & 15;
  const int tid = threadIdx.x;
  const int wave = tid >> 6;
  const int lane = tid & 63;
  const int tgrp = wave >> 1;                                   // t pair 0/1
  const int i0 = __builtin_amdgcn_readfirstlane((wave & 1) << 4); // i half
  const int tl = tgrp * 2 + lane / 25;   // local t in [0,4) (4 = inactive)
  const int tlc = tl < 4 ? tl : 3;       // clamped for address safety
  const int v = lane % 25;
  const bool act = lane < 50;
  const int tlv = tgrp * 50 + lane;      // tl*25+v flat (valid when act)

  __shared__ float a_lds[3200];          // [k=i*4+tl][v], k<128
  __shared__ float b_lds[3200];
  __shared__ float red[3][625];

  // scores-phase role: 25 5x5 tiles x 10 K-slices (250 threads)
  const int tp = tid % 25;
  const int ks = tid / 25;
  const int v5 = (tp / 5) * 5, w5 = (tp % 5) * 5;
  const int kb = (ks < 8) ? ks * 13 : (104 + (ks - 8) * 12);
  const int kcnt = (ks < 8) ? 13 : 12;

  for (int idx = tid; idx < 1875; idx += 256) (&red[0][0])[idx] = 0.0f;

  for (int sub = 0; sub < 4; ++sub) {
    const int t0 = ch * 16 + sub * 4;
    for (int s = 0; s < 3; ++s) {
      __syncthreads();  // a_lds/b_lds safe to overwrite; red zero visible
      // ---- conv: fa/fb[i] for this lane's (t,v) ----
      float fa[16], fb[16];
      #pragma unroll
      for (int j = 0; j < 16; ++j) {
        fa[j] = ba[s * 32 + i0 + j];
        fb[j] = bb[s * 32 + i0 + j];
      }
      const float* xp = x + n * 409600 + (t0 + tlc) * 25 + v;
      const float* wap = WaT + s * 2048 + i0;
      const float* wbp = WbT + s * 2048 + i0;
      for (int c = 0; c < 64; ++c) {
        float xv = act ? xp[c * 6400] : 0.0f;
        #pragma unroll
        for (int j = 0; j < 16; ++j) {
          fa[j] = fmaf(wap[c * 32 + j], xv, fa[j]);
          fb[j] = fmaf(wbp[c * 32 + j], xv, fb[j]);
        }
      }
      if (act) {
        #pragma unroll
        for (int j = 0; j < 16; ++j) {
          a_lds[(i0 + j) * 100 + tlv] = fa[j];
          b_lds[(i0 + j) * 100 + tlv] = fb[j];
        }
      }
      __syncthreads();
      // ---- scores: sc[5][5] over this thread's K slice ----
      if (tid < 250) {
        float sc[5][5];
        #pragma unroll
        for (int dv = 0; dv < 5; ++dv)
          #pragma unroll
          for (int dw = 0; dw < 5; ++dw) sc[dv][dw] = 0.0f;
        for (int kk = 0; kk < kcnt; ++kk) {
          const int k = kb + kk;
          float av[5], bv[5];
          #pragma unroll
          for (int d = 0; d < 5; ++d) {
            av[d] = a_lds[k * 25 + v5 + d];
            bv[d] = b_lds[k * 25 + w5 + d];
          }
          #pragma unroll
          for (int dv = 0; dv < 5; ++dv)
            #pragma unroll
            for (int dw = 0; dw < 5; ++dw)
              sc[dv][dw] = fmaf(av[dv], bv[dw], sc[dv][dw]);
        }
        #pragma unroll
        for (int dv = 0; dv < 5; ++dv)
          #pragma unroll
          for (int dw = 0; dw < 5; ++dw)
            atomicAdd(&red[s][(v5 + dv) * 25 + (w5 + dw)], sc[dv][dw]);
      }
    }
  }
  __syncthreads();
  for (int s = 0; s < 3; ++s)
    for (int idx = tid; idx < 625; idx += 256)
      part[((n * NCHUNK + ch) * 3 + s) * 625 + idx] = red[s][idx];
}

// -------- K2: reduce partials, /8192, softmax over v, +A, pad to 32 --------
__global__ __launch_bounds__(64) void k2_softmax(
    const float* __restrict__ part, const float* __restrict__ A,
    float* __restrict__ att)
{
  const int ns = blockIdx.x;              // 192
  const int n = ns / 3, s = ns % 3;
  const int w = threadIdx.x;
  float* ap = att + ns * 800;
  if (w < 25) {
    float sc[25];
    float m = -3.0e38f;
    #pragma unroll
    for (int v = 0; v < 25; ++v) {
      float acc = 0.0f;
      for (int chk = 0; chk < NCHUNK; ++chk)
        acc += part[((n * NCHUNK + chk) * 3 + s) * 625 + v * 25 + w];
      sc[v] = acc * (1.0f / 8192.0f);
      m = fmaxf(m, sc[v]);
    }
    float sum = 0.0f;
    #pragma unroll
    for (int v = 0; v < 25; ++v) { sc[v] = expf(sc[v] - m); sum += sc[v]; }
    const float inv = 1.0f / sum;
    #pragma unroll
    for (int v = 0; v < 25; ++v)
      ap[v * 32 + w] = sc[v] * inv + A[(s * 25 + v) * 25 + w];
  } else if (w < 32) {
    for (int v = 0; v < 25; ++v) ap[v * 32 + w] = 0.0f;  // pad lanes -> za=0
  }
}

// ----------------- K3: z = x@att, y += WdT@z, BN epilogue ------------------
// grid (n, t-pair) = 64*128 = 8192 blocks, 256 threads.
// Phase A: lanes=(c,t) 64x, regs=16 w's, att row via s_load_dwordx16.
// Phase B: lanes=(t,w) 64x, regs=16 o's, WdT row via s_load_dwordx16.
__global__ __launch_bounds__(256) void k3_out(
    const float* __restrict__ x, const float* __restrict__ att,
    const float* __restrict__ WdT,
    const float* __restrict__ alpha, const float* __restrict__ betaE,
    float* __restrict__ out)
{
  const int nb = blockIdx.x;
  const int n = nb >> 7;
  const int t0 = (nb & 127) * 2;
  const int tid = threadIdx.x;
  const int wave = tid >> 6;
  const int lane = tid & 63;

  __shared__ float xs[3200];             // [c][t*25+v]  (64 x 50)
  __shared__ float zt[4224];             // [c][t*33+w]  (stride 66, pad 33)

  const float* xg = x + n * 409600 + t0 * 25;
  for (int idx = tid; idx < 3200; idx += 256) {
    int c = idx / 50, p = idx - c * 50;
    xs[idx] = xg[c * 6400 + p];
  }

  const int c0A = __builtin_amdgcn_readfirstlane((wave & 1) << 5);
  const int w0A = __builtin_amdgcn_readfirstlane((wave >> 1) << 4);
  const int o0B = __builtin_amdgcn_readfirstlane(wave << 4);
  const int tB = lane >> 5, wB = lane & 31;
  const int xbase = c0A * 50 + lane * 25;       // (c0A+lane/2, t=lane&1)
  const int zwb   = c0A * 66 + lane * 33 + w0A; // same lane mapping
  const int zrb   = tB * 33 + wB;

  float yacc[16];
  #pragma unroll
  for (int j = 0; j < 16; ++j) yacc[j] = 0.0f;

  __syncthreads();
  for (int s = 0; s < 3; ++s) {
    // ---- phase A: zt[c][t][w0A..+15] = sum_v xs * att[v][w] ----
    const float* attp = att + (n * 3 + s) * 800 + w0A;
    float za[16];
    #pragma unroll
    for (int j = 0; j < 16; ++j) za[j] = 0.0f;
    for (int v = 0; v < 25; ++v) {
      float xv = xs[xbase + v];
      #pragma unroll
      for (int j = 0; j < 16; ++j)
        za[j] = fmaf(attp[v * 32 + j], xv, za[j]);
    }
    #pragma unroll
    for (int j = 0; j < 16; ++j) zt[zwb + j] = za[j];
    __syncthreads();
    // ---- phase B: yacc[o0B..+15] += sum_c WdT[s][c][o] * zt[c][p] ----
    const float* wdp = WdT + s * 4096 + o0B;
    for (int c = 0; c < 64; ++c) {
      float zv = zt[c * 66 + zrb];
      #pragma unroll
      for (int j = 0; j < 16; ++j)
        yacc[j] = fmaf(wdp[c * 64 + j], zv, yacc[j]);
    }
    __syncthreads();
  }
  if (wB < 25) {
    const int t = t0 + tB;
    float* op = out + n * 409600 + t * 25 + wB;
    #pragma unroll
    for (int j = 0; j < 16; ++j) {
      const int o = o0B + j;
      op[o * 6400] = alpha[o] * yacc[j] + betaE[o];
    }
  }
}

// ---------------------------------------------------------------------------
extern "C" void kernel_launch(void* const* d_in, const int* in_sizes, int n_in,
                              void* d_out, int out_size, void* d_ws, size_t ws_size,
                              hipStream_t stream) {
  const float* x     = (const float*)d_in[0];
  const float* A     = (const float*)d_in[1];
  const float* Wa    = (const float*)d_in[2];
  const float* ba    = (const float*)d_in[3];
  const float* Wb    = (const float*)d_in[4];
  const float* bb    = (const float*)d_in[5];
  const float* Wd    = (const float*)d_in[6];
  const float* bd    = (const float*)d_in[7];
  const float* gamma = (const float*)d_in[8];
  const float* beta  = (const float*)d_in[9];
  float* wsf = (float*)d_ws;
  float* out = (float*)d_out;

  k0_prep<<<64, 256, 0, stream>>>(wsf, Wa, Wb, Wd, bd, gamma, beta);
  k1_scores<<<1024, 256, 0, stream>>>(x, wsf + WAT_OFF, wsf + WBT_OFF,
                                      ba, bb, wsf + PART_OFF);
  k2_softmax<<<192, 64, 0, stream>>>(wsf + PART_OFF, A, wsf + ATT_OFF);
  k3_out<<<8192, 256, 0, stream>>>(x, wsf + ATT_OFF, wsf + WDT_OFF,
                                   wsf + ALPHA_OFF, wsf + BETA_OFF, out);
}

// Round 4
// 571.224 us; speedup vs baseline: 1.7232x; 1.7232x over previous
//
#include <hip/hip_runtime.h>

// ---------------------------------------------------------------------------
// AGCN block: a/b 1x1 convs -> scores -> softmax(+A) -> z = x@att -> y = Wd@z
// N=64 C=64 T=256 V=25 S=3 OC=64 IC=32. All fp32 (no fp32 MFMA on CDNA4 ->
// vector-ALU bound, floor ~166us @157TF).
// R3 post-mortem: K1 was latency-bound (VALUBusy 19%, 1.2e7 LDS conflicts,
// VGPR=68 -> no load ILP). R4: 8-deep pipelined x loads, atomic-free scores
// reduction (per-ks LDS scratch + owner-thread sum), K3 unroll pragmas.
// ---------------------------------------------------------------------------

#define NCHUNK    16                     // t-chunks per n in K1
#define ATT_OFF   0                      // [N][S][25][32] padded att
#define ATT_SZ    (64*3*25*32)           // 153600
#define PART_OFF  153600                 // [N][NCHUNK][S][625] score partials
#define PART_SZ   (64*NCHUNK*3*625)      // 1920000
#define WAT_OFF   (PART_OFF + PART_SZ)   // [S][C][IC]
#define WBT_OFF   (WAT_OFF + 3*64*32)    // [S][C][IC]
#define WDT_OFF   (WBT_OFF + 3*64*32)    // [S][C][OC]
#define ALPHA_OFF (WDT_OFF + 3*64*64)    // [OC]
#define BETA_OFF  (ALPHA_OFF + 64)       // [OC]
// total ws: ~2.1M floats = 8.4 MB

// --------------------------- K0: weight prep -------------------------------
__global__ __launch_bounds__(256) void k0_prep(
    float* __restrict__ wsf,
    const float* __restrict__ Wa, const float* __restrict__ Wb,
    const float* __restrict__ Wd, const float* __restrict__ bd,
    const float* __restrict__ gamma, const float* __restrict__ beta)
{
  int idx = blockIdx.x * 256 + threadIdx.x;
  if (idx < 6144) {                       // WaT/WbT: [s][c][i] <- [s][i][c]
    int s = idx / 2048, r = idx - s * 2048, c = r >> 5, i = r & 31;
    wsf[WAT_OFF + idx] = Wa[s * 2048 + i * 64 + c];
    wsf[WBT_OFF + idx] = Wb[s * 2048 + i * 64 + c];
  }
  if (idx < 12288) {                      // WdT: [s][c][o] <- [s][o][c]
    int s = idx / 4096, r = idx - s * 4096, c = r >> 6, o = r & 63;
    wsf[WDT_OFF + idx] = Wd[s * 4096 + o * 64 + c];
  }
  if (idx < 64) {                         // fused BN(inference) + bias-sum
    float al = gamma[idx] * rsqrtf(1.0f + 1e-5f);
    wsf[ALPHA_OFF + idx] = al;
    float bs = bd[idx] + bd[64 + idx] + bd[128 + idx];
    wsf[BETA_OFF + idx] = beta[idx] + al * bs;
  }
}

// ------------------- K1: conv a,b + score partial accumulation -------------
// grid (n, chunk of 16 t) = 1024 blocks, 256 threads, 33KB LDS (4 blk/CU).
// Per (sub,s): conv 4 t's with 8-deep pipelined x loads (L1-hot for s>=1),
// 5x5-reg-tiled scores, then ATOMIC-FREE reduction: sc tiles -> red2[ks][625]
// (aliased on a/b LDS) -> owner thread sums 10 slices into red[s][vw].
__global__ __launch_bounds__(256) void k1_scores(
    const float* __restrict__ x,
    const float* __restrict__ WaT, const float* __restrict__ WbT,
    const float* __restrict__ ba, const float* __restrict__ bb,
    float* __restrict__ part)
{
  const int nb = blockIdx.x;
  const int n = nb >> 4;
  const int ch = nb & 15;
  const int tid = threadIdx.x;
  const int wave = tid >> 6;
  const int lane = tid & 63;
  const int tgrp = wave >> 1;                                     // t pair
  const int i0 = __builtin_amdgcn_readfirstlane((wave & 1) << 4); // i half
  const int tl = tgrp * 2 + lane / 25;   // local t in [0,4) (4 = inactive)
  const int tlc = tl < 4 ? tl : 3;       // clamped for address safety
  const int v = lane % 25;
  const bool act = lane < 50;
  const int tlv = tgrp * 50 + lane;      // == tl*25+v when act

  __shared__ float ab[6400];             // a: [0,3200) b: [3200,6400)
                                         // layout [i][tl*25+v] == [k=i*4+tl][v]
  __shared__ float red[1875];            // [s][625] accumulators
  float* const red2 = ab;                // [ks][625] scratch (6250<=6400)

  // scores-phase role: 25 5x5 tiles x 10 K-slices (250 threads)
  const int tp = tid % 25;
  const int ks = tid / 25;
  const int v5 = (tp / 5) * 5, w5 = (tp % 5) * 5;
  const int kb = (ks < 8) ? ks * 13 : (104 + (ks - 8) * 12);
  const int kcnt = (ks < 8) ? 13 : 12;

  for (int idx = tid; idx < 1875; idx += 256) red[idx] = 0.0f;
  __syncthreads();

  for (int sub = 0; sub < 4; ++sub) {
    const int t0 = ch * 16 + sub * 4;
    for (int s = 0; s < 3; ++s) {
      // ---- conv: fa/fb[i] for this lane's (t,v), 8-deep load pipeline ----
      float fa[16], fb[16];
      #pragma unroll
      for (int j = 0; j < 16; ++j) {
        fa[j] = ba[s * 32 + i0 + j];
        fb[j] = bb[s * 32 + i0 + j];
      }
      const float* xp = x + n * 409600 + (t0 + tlc) * 25 + v;
      const float* wap = WaT + s * 2048 + i0;
      const float* wbp = WbT + s * 2048 + i0;
      for (int c8 = 0; c8 < 64; c8 += 8) {
        float xv[8];
        #pragma unroll
        for (int u = 0; u < 8; ++u)
          xv[u] = act ? xp[(c8 + u) * 6400] : 0.0f;
        #pragma unroll
        for (int u = 0; u < 8; ++u) {
          const float* wa8 = wap + (c8 + u) * 32;
          const float* wb8 = wbp + (c8 + u) * 32;
          #pragma unroll
          for (int j = 0; j < 16; ++j) {
            fa[j] = fmaf(wa8[j], xv[u], fa[j]);
            fb[j] = fmaf(wb8[j], xv[u], fb[j]);
          }
        }
      }
      __syncthreads();  // prev iteration's red2 reads done -> ab writable
      if (act) {
        #pragma unroll
        for (int j = 0; j < 16; ++j) {
          ab[(i0 + j) * 100 + tlv]        = fa[j];
          ab[3200 + (i0 + j) * 100 + tlv] = fb[j];
        }
      }
      __syncthreads();
      // ---- scores: sc[5][5] over this thread's K slice ----
      float sc[5][5];
      if (tid < 250) {
        #pragma unroll
        for (int dv = 0; dv < 5; ++dv)
          #pragma unroll
          for (int dw = 0; dw < 5; ++dw) sc[dv][dw] = 0.0f;
        for (int kk = 0; kk < kcnt; ++kk) {
          const int k = kb + kk;
          float av[5], bv[5];
          #pragma unroll
          for (int d = 0; d < 5; ++d) {
            av[d] = ab[k * 25 + v5 + d];
            bv[d] = ab[3200 + k * 25 + w5 + d];
          }
          #pragma unroll
          for (int dv = 0; dv < 5; ++dv)
            #pragma unroll
            for (int dw = 0; dw < 5; ++dw)
              sc[dv][dw] = fmaf(av[dv], bv[dw], sc[dv][dw]);
        }
      }
      __syncthreads();  // a/b reads done -> red2 (aliased) writable
      if (tid < 250) {
        #pragma unroll
        for (int dv = 0; dv < 5; ++dv)
          #pragma unroll
          for (int dw = 0; dw < 5; ++dw)
            red2[ks * 625 + (v5 + dv) * 25 + (w5 + dw)] = sc[dv][dw];
      }
      __syncthreads();
      // ---- owner-thread reduction over ks (atomic-free) ----
      {
        float acc0 = 0.0f, acc1 = 0.0f, acc2 = 0.0f;
        #pragma unroll
        for (int q = 0; q < 10; ++q) {
          acc0 += red2[q * 625 + tid];
          acc1 += red2[q * 625 + tid + 256];
          if (tid < 113) acc2 += red2[q * 625 + tid + 512];
        }
        red[s * 625 + tid]        += acc0;
        red[s * 625 + tid + 256]  += acc1;
        if (tid < 113) red[s * 625 + tid + 512] += acc2;
      }
    }
  }
  __syncthreads();
  for (int s = 0; s < 3; ++s)
    for (int idx = tid; idx < 625; idx += 256)
      part[((n * NCHUNK + ch) * 3 + s) * 625 + idx] = red[s * 625 + idx];
}

// -------- K2: reduce partials, /8192, softmax over v, +A, pad to 32 --------
__global__ __launch_bounds__(64) void k2_softmax(
    const float* __restrict__ part, const float* __restrict__ A,
    float* __restrict__ att)
{
  const int ns = blockIdx.x;              // 192
  const int n = ns / 3, s = ns % 3;
  const int w = threadIdx.x;
  float* ap = att + ns * 800;
  if (w < 25) {
    float sc[25];
    float m = -3.0e38f;
    #pragma unroll
    for (int v = 0; v < 25; ++v) {
      float acc = 0.0f;
      for (int chk = 0; chk < NCHUNK; ++chk)
        acc += part[((n * NCHUNK + chk) * 3 + s) * 625 + v * 25 + w];
      sc[v] = acc * (1.0f / 8192.0f);
      m = fmaxf(m, sc[v]);
    }
    float sum = 0.0f;
    #pragma unroll
    for (int v = 0; v < 25; ++v) { sc[v] = expf(sc[v] - m); sum += sc[v]; }
    const float inv = 1.0f / sum;
    #pragma unroll
    for (int v = 0; v < 25; ++v)
      ap[v * 32 + w] = sc[v] * inv + A[(s * 25 + v) * 25 + w];
  } else if (w < 32) {
    for (int v = 0; v < 25; ++v) ap[v * 32 + w] = 0.0f;  // pad lanes -> za=0
  }
}

// ----------------- K3: z = x@att, y += WdT@z, BN epilogue ------------------
// grid (n, t-pair) = 64*128 = 8192 blocks, 256 threads.
// Phase A: lanes=(c,t) 64x, regs=16 w's, att row via s_load_dwordx16.
// Phase B: lanes=(t,w) 64x, regs=16 o's, WdT row via s_load_dwordx16.
// Unroll pragmas batch the serial s_load->fma chains (R3: latency-stalled).
__global__ __launch_bounds__(256) void k3_out(
    const float* __restrict__ x, const float* __restrict__ att,
    const float* __restrict__ WdT,
    const float* __restrict__ alpha, const float* __restrict__ betaE,
    float* __restrict__ out)
{
  const int nb = blockIdx.x;
  const int n = nb >> 7;
  const int t0 = (nb & 127) * 2;
  const int tid = threadIdx.x;
  const int wave = tid >> 6;
  const int lane = tid & 63;

  __shared__ float xs[3200];             // [c][t*25+v]  (64 x 50)
  __shared__ float zt[4224];             // [c][t*33+w]  (stride 66, pad 33)

  const float* xg = x + n * 409600 + t0 * 25;
  for (int idx = tid; idx < 3200; idx += 256) {
    int c = idx / 50, p = idx - c * 50;
    xs[idx] = xg[c * 6400 + p];
  }

  const int c0A = __builtin_amdgcn_readfirstlane((wave & 1) << 5);
  const int w0A = __builtin_amdgcn_readfirstlane((wave >> 1) << 4);
  const int o0B = __builtin_amdgcn_readfirstlane(wave << 4);
  const int tB = lane >> 5, wB = lane & 31;
  const int xbase = c0A * 50 + lane * 25;       // (c0A+lane/2, t=lane&1)
  const int zwb   = c0A * 66 + lane * 33 + w0A; // same lane mapping
  const int zrb   = tB * 33 + wB;

  float yacc[16];
  #pragma unroll
  for (int j = 0; j < 16; ++j) yacc[j] = 0.0f;

  __syncthreads();
  for (int s = 0; s < 3; ++s) {
    // ---- phase A: zt[c][t][w0A..+15] = sum_v xs * att[v][w] ----
    const float* attp = att + (n * 3 + s) * 800 + w0A;
    float za[16];
    #pragma unroll
    for (int j = 0; j < 16; ++j) za[j] = 0.0f;
    #pragma unroll 5
    for (int v = 0; v < 25; ++v) {
      float xv = xs[xbase + v];
      #pragma unroll
      for (int j = 0; j < 16; ++j)
        za[j] = fmaf(attp[v * 32 + j], xv, za[j]);
    }
    #pragma unroll
    for (int j = 0; j < 16; ++j) zt[zwb + j] = za[j];
    __syncthreads();
    // ---- phase B: yacc[o0B..+15] += sum_c WdT[s][c][o] * zt[c][p] ----
    const float* wdp = WdT + s * 4096 + o0B;
    #pragma unroll 4
    for (int c = 0; c < 64; ++c) {
      float zv = zt[c * 66 + zrb];
      #pragma unroll
      for (int j = 0; j < 16; ++j)
        yacc[j] = fmaf(wdp[c * 64 + j], zv, yacc[j]);
    }
    __syncthreads();
  }
  if (wB < 25) {
    const int t = t0 + tB;
    float* op = out + n * 409600 + t * 25 + wB;
    #pragma unroll
    for (int j = 0; j < 16; ++j) {
      const int o = o0B + j;
      op[o * 6400] = alpha[o] * yacc[j] + betaE[o];
    }
  }
}

// ---------------------------------------------------------------------------
extern "C" void kernel_launch(void* const* d_in, const int* in_sizes, int n_in,
                              void* d_out, int out_size, void* d_ws, size_t ws_size,
                              hipStream_t stream) {
  const float* x     = (const float*)d_in[0];
  const float* A     = (const float*)d_in[1];
  const float* Wa    = (const float*)d_in[2];
  const float* ba    = (const float*)d_in[3];
  const float* Wb    = (const float*)d_in[4];
  const float* bb    = (const float*)d_in[5];
  const float* Wd    = (const float*)d_in[6];
  const float* bd    = (const float*)d_in[7];
  const float* gamma = (const float*)d_in[8];
  const float* beta  = (const float*)d_in[9];
  float* wsf = (float*)d_ws;
  float* out = (float*)d_out;

  k0_prep<<<64, 256, 0, stream>>>(wsf, Wa, Wb, Wd, bd, gamma, beta);
  k1_scores<<<1024, 256, 0, stream>>>(x, wsf + WAT_OFF, wsf + WBT_OFF,
                                      ba, bb, wsf + PART_OFF);
  k2_softmax<<<192, 64, 0, stream>>>(wsf + PART_OFF, A, wsf + ATT_OFF);
  k3_out<<<8192, 256, 0, stream>>>(x, wsf + ATT_OFF, wsf + WDT_OFF,
                                   wsf + ALPHA_OFF, wsf + BETA_OFF, out);
}